// Round 1
// baseline (229.426 us; speedup 1.0000x reference)
//
#include <hip/hip_runtime.h>

// DenseCaps EM routing: B=32, I=2048, O=64, P=4, D=16, 3 EM iterations.
// Fused design: votes V are recomputed on the fly (never hit HBM).
// lane (0..63) <-> output capsule o; softmax over O = wave-wide shuffle reduce.
constexpr int Bn = 32;
constexpr int In = 2048;
constexpr int On = 64;
constexpr float EPSF = 1e-7f;
constexpr int CCH = 16;          // i-chunks per batch image
constexpr int IPB = In / CCH;    // 128 i per block
constexpr int IPW = IPB / 4;     // 32 i per wave (4 waves/block)

// Workspace layout (floats):
//   w_t      [In][On][16]      : 2,097,152   (8 MB)
//   partials [Bn][CCH][33][On] : 1,081,344   (4.3 MB)
//   params   [Bn*On][36]       :    73,728   (0.3 MB)
// total ~12.4 MB

__global__ __launch_bounds__(256) void transpose_w_k(const float4* __restrict__ w,
                                                     float4* __restrict__ w_t) {
  int idx = blockIdx.x * 256 + threadIdx.x;  // 0 .. In*On*4-1
  int d4 = idx & 3;
  int rest = idx >> 2;   // i*64 + o
  int o = rest & 63;
  int i = rest >> 6;
  // read w[o][i][d4] (float4 granularity), write w_t[i][o][d4] contiguously
  w_t[idx] = w[((size_t)((o << 11) + i)) * 4 + d4];
}

template <int TPASS>
__global__ __launch_bounds__(256) void pass_k(const float* __restrict__ poses,
                                              const float* __restrict__ a_in,
                                              const float* __restrict__ w_t,
                                              const float* __restrict__ params,
                                              float* __restrict__ partials) {
  const int b = blockIdx.x;      // batch fastest -> co-resident blocks share w_t chunk in L2
  const int c = blockIdx.y;      // i-chunk
  const int tid = threadIdx.x;
  const int wv = tid >> 6;
  const int ln = tid & 63;       // lane == output capsule o

  // Per-lane (= per-o) constants from previous iteration
  float mu[16], hs[16], c0 = 0.f;
  if (TPASS > 0) {
    const float* pp = params + (size_t)(b * 64 + ln) * 36;
    const float4* pp4 = (const float4*)pp;
#pragma unroll
    for (int k = 0; k < 4; ++k) {
      float4 v = pp4[k];
      mu[4 * k] = v.x; mu[4 * k + 1] = v.y; mu[4 * k + 2] = v.z; mu[4 * k + 3] = v.w;
    }
#pragma unroll
    for (int k = 0; k < 4; ++k) {
      float4 v = pp4[4 + k];
      hs[4 * k] = v.x; hs[4 * k + 1] = v.y; hs[4 * k + 2] = v.z; hs[4 * k + 3] = v.w;
    }
    c0 = pp[32];
  }

  float rs = 0.f, S1[16], S2[16];
#pragma unroll
  for (int d = 0; d < 16; ++d) { S1[d] = 0.f; S2[d] = 0.f; }

  const float4* wt4 = (const float4*)w_t;
  const float4* po4 = (const float4*)poses;
  const int i0 = c * IPB + wv * IPW;

  for (int ii = 0; ii < IPW; ++ii) {
    const int i = i0 + ii;
    float P[16], W[16], V[16];
#pragma unroll
    for (int k = 0; k < 4; ++k) {  // poses[b,i,:] broadcast to all lanes
      float4 v = po4[(size_t)(b * In + i) * 4 + k];
      P[4 * k] = v.x; P[4 * k + 1] = v.y; P[4 * k + 2] = v.z; P[4 * k + 3] = v.w;
    }
#pragma unroll
    for (int k = 0; k < 4; ++k) {  // w_t[i, lane, :]
      float4 v = wt4[(size_t)((i << 6) + ln) * 4 + k];
      W[4 * k] = v.x; W[4 * k + 1] = v.y; W[4 * k + 2] = v.z; W[4 * k + 3] = v.w;
    }
    // V = P(4x4) @ W(4x4): V[p,r] = sum_q P[p,q] W[q,r]
#pragma unroll
    for (int p = 0; p < 4; ++p) {
#pragma unroll
      for (int r = 0; r < 4; ++r) {
        float acc = P[p * 4] * W[r];
        acc = fmaf(P[p * 4 + 1], W[4 + r], acc);
        acc = fmaf(P[p * 4 + 2], W[8 + r], acc);
        acc = fmaf(P[p * 4 + 3], W[12 + r], acc);
        V[p * 4 + r] = acc;
      }
    }
    const float a = a_in[b * In + i];
    float r;
    if (TPASS == 0) {
      r = a * (1.f / 64.f);  // R uniform at t=0
    } else {
      // u = log(a_out+eps) - 0.5*sum log(sig2) - sum diff^2 * (0.5/sig2)
      float u = c0;
#pragma unroll
      for (int d = 0; d < 16; ++d) {
        float df = V[d] - mu[d];
        u = fmaf(-df * df, hs[d], u);
      }
      // softmax over o == wave-wide reduce (64 lanes)
      float m = u;
#pragma unroll
      for (int k = 1; k < 64; k <<= 1) m = fmaxf(m, __shfl_xor(m, k));
      float e = __expf(u - m);
      float s = e;
#pragma unroll
      for (int k = 1; k < 64; k <<= 1) s += __shfl_xor(s, k);
      r = a * e / s;
    }
    rs += r;
#pragma unroll
    for (int d = 0; d < 16; ++d) {
      float t1 = r * V[d];
      S1[d] += t1;                      // sum r*V
      S2[d] = fmaf(t1, V[d], S2[d]);    // sum r*V^2
    }
  }

  // Reduce 4 waves -> one partial per (b, c, j, o)
  __shared__ float lds[4][33][64];
  lds[wv][0][ln] = rs;
#pragma unroll
  for (int d = 0; d < 16; ++d) {
    lds[wv][1 + d][ln] = S1[d];
    lds[wv][17 + d][ln] = S2[d];
  }
  __syncthreads();
  for (int idx = tid; idx < 33 * 64; idx += 256) {
    int j = idx >> 6, o = idx & 63;
    float s = lds[0][j][o] + lds[1][j][o] + lds[2][j][o] + lds[3][j][o];
    partials[((size_t)(b * CCH + c) * 33 + j) * 64 + o] = s;
  }
}

template <int TPASS>
__global__ __launch_bounds__(256) void finalize_k(const float* __restrict__ partials,
                                                  const float* __restrict__ beta_a,
                                                  const float* __restrict__ beta_u,
                                                  float* __restrict__ params,
                                                  float* __restrict__ out) {
  const int g = blockIdx.x * 256 + threadIdx.x;  // 0..Bn*On-1
  const int b = g >> 6, o = g & 63;
  float rs = 0.f, S1[16], S2[16];
#pragma unroll
  for (int d = 0; d < 16; ++d) { S1[d] = 0.f; S2[d] = 0.f; }
  for (int c = 0; c < CCH; ++c) {
    const float* base = partials + (size_t)(b * CCH + c) * 33 * 64 + o;
    rs += base[0];
#pragma unroll
    for (int d = 0; d < 16; ++d) S1[d] += base[(1 + d) * 64];
#pragma unroll
    for (int d = 0; d < 16; ++d) S2[d] += base[(17 + d) * 64];
  }
  const float r_sum = rs + EPSF;
  const float inv = 1.f / r_sum;
  float lsum = 0.f;
  float muv[16], sg[16];
#pragma unroll
  for (int d = 0; d < 16; ++d) {
    float m = S1[d] * inv;
    float s2 = fmaxf(S2[d] * inv - m * m, 0.f) + EPSF;  // E[V^2]-mu^2 identity
    muv[d] = m;
    sg[d] = s2;
    lsum += logf(s2);
  }
  const float bu = beta_u[o], ba = beta_a[o];
  const float cost = (16.f * bu + 0.5f * lsum) * r_sum;
  const float it = (float)(TPASS + 1);
  const float aout = 1.f / (1.f + expf(-it * (ba - cost)));
  if (TPASS < 2) {
    float* pp = params + (size_t)g * 36;
#pragma unroll
    for (int d = 0; d < 16; ++d) {
      pp[d] = muv[d];
      pp[16 + d] = 0.5f / sg[d];
    }
    pp[32] = logf(aout + EPSF) - 0.5f * lsum;
  } else {
#pragma unroll
    for (int d = 0; d < 16; ++d) out[(size_t)g * 16 + d] = muv[d];
    out[Bn * On * 16 + g] = aout;
  }
}

extern "C" void kernel_launch(void* const* d_in, const int* in_sizes, int n_in,
                              void* d_out, int out_size, void* d_ws, size_t ws_size,
                              hipStream_t stream) {
  const float* poses  = (const float*)d_in[0];
  const float* a_in   = (const float*)d_in[1];
  const float* w      = (const float*)d_in[2];
  const float* beta_a = (const float*)d_in[3];
  const float* beta_u = (const float*)d_in[4];
  float* out = (float*)d_out;

  float* w_t      = (float*)d_ws;
  float* partials = w_t + (size_t)In * On * 16;
  float* params   = partials + (size_t)Bn * CCH * 33 * 64;

  transpose_w_k<<<dim3(In * On * 4 / 256), 256, 0, stream>>>((const float4*)w, (float4*)w_t);

  dim3 pg(Bn, CCH);  // b fastest for L2 sharing of w_t
  pass_k<0><<<pg, 256, 0, stream>>>(poses, a_in, w_t, params, partials);
  finalize_k<0><<<Bn * On / 256, 256, 0, stream>>>(partials, beta_a, beta_u, params, out);
  pass_k<1><<<pg, 256, 0, stream>>>(poses, a_in, w_t, params, partials);
  finalize_k<1><<<Bn * On / 256, 256, 0, stream>>>(partials, beta_a, beta_u, params, out);
  pass_k<2><<<pg, 256, 0, stream>>>(poses, a_in, w_t, params, partials);
  finalize_k<2><<<Bn * On / 256, 256, 0, stream>>>(partials, beta_a, beta_u, params, out);
}

// Round 2
// 206.312 us; speedup vs baseline: 1.1120x; 1.1120x over previous
//
#include <hip/hip_runtime.h>

// DenseCaps EM routing: B=32, I=2048, O=64, P=4, D=16, 3 EM iterations.
// Fused: votes V recomputed on the fly; lane <-> output capsule o; softmax
// over O = wave-wide shuffle reduce. v2: 4x grid, unroll-2 interleaved
// softmax chains, coalesced w_t layout, parallel chunk-reduce.
constexpr int Bn = 32;
constexpr int In = 2048;
constexpr int On = 64;
constexpr float EPSF = 1e-7f;
constexpr int CCH = 64;          // i-chunks per batch image
constexpr int IPB = In / CCH;    // 32 i per block
constexpr int IPW = IPB / 4;     // 8 i per wave (4 waves/block)

// Workspace (floats):
//   w_t      [In][4][On][4]    : 2,097,152  (8 MB)    w_t[i][k][o] = w[o][i][k-th float4]
//   partials [Bn][CCH][33][On] : 4,325,376  (17.3 MB)
//   red      [Bn][33][On]      :    67,584  (0.27 MB)
//   params   [Bn*On][36]       :    73,728  (0.3 MB)

__global__ __launch_bounds__(256) void transpose_w_k(const float4* __restrict__ w,
                                                     float4* __restrict__ w_t) {
  int idx = blockIdx.x * 256 + threadIdx.x;  // input float4 index: o*8192 + i*4 + k
  int o = idx >> 13;
  int rest = idx & 8191;
  int i = rest >> 2;
  int k = rest & 3;
  // coalesced read, scattered 16B write (one-shot, ~8 MB)
  w_t[(size_t)((i << 2) + k) * 64 + o] = w[idx];
}

template <int TPASS>
__global__ __launch_bounds__(256, 4) void pass_k(const float* __restrict__ poses,
                                                 const float* __restrict__ a_in,
                                                 const float* __restrict__ w_t,
                                                 const float* __restrict__ params,
                                                 float* __restrict__ partials) {
  const int b = blockIdx.x;      // batch fastest -> co-resident blocks share w_t chunk
  const int c = blockIdx.y;      // i-chunk
  const int tid = threadIdx.x;
  const int wv = tid >> 6;
  const int ln = tid & 63;       // lane == output capsule o

  float mu[16], hs[16], c0 = 0.f;
  if (TPASS > 0) {
    const float* pp = params + (size_t)(b * 64 + ln) * 36;
    const float4* pp4 = (const float4*)pp;
#pragma unroll
    for (int k = 0; k < 4; ++k) {
      float4 v = pp4[k];
      mu[4 * k] = v.x; mu[4 * k + 1] = v.y; mu[4 * k + 2] = v.z; mu[4 * k + 3] = v.w;
    }
#pragma unroll
    for (int k = 0; k < 4; ++k) {
      float4 v = pp4[4 + k];
      hs[4 * k] = v.x; hs[4 * k + 1] = v.y; hs[4 * k + 2] = v.z; hs[4 * k + 3] = v.w;
    }
    c0 = pp[32];
  }

  float rs = 0.f, S1[16], S2[16];
#pragma unroll
  for (int d = 0; d < 16; ++d) { S1[d] = 0.f; S2[d] = 0.f; }

  const float4* wt4 = (const float4*)w_t;
  const float4* po4 = (const float4*)poses;
  const int i0 = c * IPB + wv * IPW;

  for (int ii = 0; ii < IPW; ii += 2) {
    const int ia = i0 + ii;
    float P0[16], W0[16], V0[16], P1[16], W1[16], V1[16];
#pragma unroll
    for (int k = 0; k < 4; ++k) {  // poses broadcast (lane-uniform -> scalarized)
      float4 v = po4[(size_t)(b * In + ia) * 4 + k];
      P0[4 * k] = v.x; P0[4 * k + 1] = v.y; P0[4 * k + 2] = v.z; P0[4 * k + 3] = v.w;
      float4 u = po4[(size_t)(b * In + ia + 1) * 4 + k];
      P1[4 * k] = u.x; P1[4 * k + 1] = u.y; P1[4 * k + 2] = u.z; P1[4 * k + 3] = u.w;
    }
#pragma unroll
    for (int k = 0; k < 4; ++k) {  // w_t[i][k][ln] -- fully coalesced (1KB/instr)
      float4 v = wt4[(size_t)((ia << 2) + k) * 64 + ln];
      W0[4 * k] = v.x; W0[4 * k + 1] = v.y; W0[4 * k + 2] = v.z; W0[4 * k + 3] = v.w;
      float4 u = wt4[(size_t)(((ia + 1) << 2) + k) * 64 + ln];
      W1[4 * k] = u.x; W1[4 * k + 1] = u.y; W1[4 * k + 2] = u.z; W1[4 * k + 3] = u.w;
    }
#pragma unroll
    for (int p = 0; p < 4; ++p) {
#pragma unroll
      for (int r = 0; r < 4; ++r) {
        float acc = P0[p * 4] * W0[r];
        acc = fmaf(P0[p * 4 + 1], W0[4 + r], acc);
        acc = fmaf(P0[p * 4 + 2], W0[8 + r], acc);
        acc = fmaf(P0[p * 4 + 3], W0[12 + r], acc);
        V0[p * 4 + r] = acc;
        float bcc = P1[p * 4] * W1[r];
        bcc = fmaf(P1[p * 4 + 1], W1[4 + r], bcc);
        bcc = fmaf(P1[p * 4 + 2], W1[8 + r], bcc);
        bcc = fmaf(P1[p * 4 + 3], W1[12 + r], bcc);
        V1[p * 4 + r] = bcc;
      }
    }
    const float a0 = a_in[b * In + ia];
    const float a1 = a_in[b * In + ia + 1];
    float r0, r1;
    if (TPASS == 0) {
      r0 = a0 * (1.f / 64.f);
      r1 = a1 * (1.f / 64.f);
    } else {
      float u0 = c0, u1 = c0;
#pragma unroll
      for (int d = 0; d < 16; ++d) {
        float df0 = V0[d] - mu[d];
        u0 = fmaf(-df0 * df0, hs[d], u0);
        float df1 = V1[d] - mu[d];
        u1 = fmaf(-df1 * df1, hs[d], u1);
      }
      // two independent wave-wide softmax chains, interleaved for ILP
      float m0 = u0, m1 = u1;
#pragma unroll
      for (int k = 1; k < 64; k <<= 1) {
        m0 = fmaxf(m0, __shfl_xor(m0, k));
        m1 = fmaxf(m1, __shfl_xor(m1, k));
      }
      float e0 = __expf(u0 - m0), e1 = __expf(u1 - m1);
      float s0 = e0, s1 = e1;
#pragma unroll
      for (int k = 1; k < 64; k <<= 1) {
        s0 += __shfl_xor(s0, k);
        s1 += __shfl_xor(s1, k);
      }
      r0 = a0 * e0 / s0;
      r1 = a1 * e1 / s1;
    }
    rs += r0 + r1;
#pragma unroll
    for (int d = 0; d < 16; ++d) {
      float t0 = r0 * V0[d];
      S1[d] += t0;
      S2[d] = fmaf(t0, V0[d], S2[d]);
      float t1 = r1 * V1[d];
      S1[d] += t1;
      S2[d] = fmaf(t1, V1[d], S2[d]);
    }
  }

  // Reduce 4 waves -> one partial per (b, c, j, o)
  __shared__ float lds[4][33][64];
  lds[wv][0][ln] = rs;
#pragma unroll
  for (int d = 0; d < 16; ++d) {
    lds[wv][1 + d][ln] = S1[d];
    lds[wv][17 + d][ln] = S2[d];
  }
  __syncthreads();
  for (int idx = tid; idx < 33 * 64; idx += 256) {
    int j = idx >> 6, o = idx & 63;
    float s = lds[0][j][o] + lds[1][j][o] + lds[2][j][o] + lds[3][j][o];
    partials[((size_t)(b * CCH + c) * 33 + j) * 64 + o] = s;
  }
}

__global__ __launch_bounds__(256) void reduce_k(const float* __restrict__ partials,
                                                float* __restrict__ red) {
  const int idx = blockIdx.x * 256 + threadIdx.x;  // (b*33 + j)*64 + o
  const int b = idx / (33 * 64);
  const float* base = partials + (size_t)b * CCH * 33 * 64 + (idx - b * 33 * 64);
  float s = 0.f;
#pragma unroll 4
  for (int c = 0; c < CCH; ++c) s += base[(size_t)c * 33 * 64];
  red[idx] = s;
}

template <int TPASS>
__global__ __launch_bounds__(256) void finalize_k(const float* __restrict__ red,
                                                  const float* __restrict__ beta_a,
                                                  const float* __restrict__ beta_u,
                                                  float* __restrict__ params,
                                                  float* __restrict__ out) {
  const int g = blockIdx.x * 256 + threadIdx.x;  // 0..Bn*On-1
  const int b = g >> 6, o = g & 63;
  const float* base = red + (size_t)b * 33 * 64 + o;
  float rs = base[0];
  const float r_sum = rs + EPSF;
  const float inv = 1.f / r_sum;
  float lsum = 0.f;
  float muv[16], sg[16];
#pragma unroll
  for (int d = 0; d < 16; ++d) {
    float S1 = base[(1 + d) * 64];
    float S2 = base[(17 + d) * 64];
    float m = S1 * inv;
    float s2 = fmaxf(S2 * inv - m * m, 0.f) + EPSF;  // E[V^2]-mu^2 identity
    muv[d] = m;
    sg[d] = s2;
    lsum += logf(s2);
  }
  const float bu = beta_u[o], ba = beta_a[o];
  const float cost = (16.f * bu + 0.5f * lsum) * r_sum;
  const float it = (float)(TPASS + 1);
  const float aout = 1.f / (1.f + expf(-it * (ba - cost)));
  if (TPASS < 2) {
    float* pp = params + (size_t)g * 36;
#pragma unroll
    for (int d = 0; d < 16; ++d) {
      pp[d] = muv[d];
      pp[16 + d] = 0.5f / sg[d];
    }
    pp[32] = logf(aout + EPSF) - 0.5f * lsum;
  } else {
#pragma unroll
    for (int d = 0; d < 16; ++d) out[(size_t)g * 16 + d] = muv[d];
    out[Bn * On * 16 + g] = aout;
  }
}

extern "C" void kernel_launch(void* const* d_in, const int* in_sizes, int n_in,
                              void* d_out, int out_size, void* d_ws, size_t ws_size,
                              hipStream_t stream) {
  const float* poses  = (const float*)d_in[0];
  const float* a_in   = (const float*)d_in[1];
  const float* w      = (const float*)d_in[2];
  const float* beta_a = (const float*)d_in[3];
  const float* beta_u = (const float*)d_in[4];
  float* out = (float*)d_out;

  float* w_t      = (float*)d_ws;
  float* partials = w_t + (size_t)In * On * 16;
  float* red      = partials + (size_t)Bn * CCH * 33 * 64;
  float* params   = red + (size_t)Bn * 33 * 64;

  transpose_w_k<<<dim3(In * On * 4 / 256), 256, 0, stream>>>((const float4*)w, (float4*)w_t);

  dim3 pg(Bn, CCH);  // b fastest for L2 sharing of w_t
  dim3 rg(Bn * 33 * 64 / 256);
  pass_k<0><<<pg, 256, 0, stream>>>(poses, a_in, w_t, params, partials);
  reduce_k<<<rg, 256, 0, stream>>>(partials, red);
  finalize_k<0><<<Bn * On / 256, 256, 0, stream>>>(red, beta_a, beta_u, params, out);
  pass_k<1><<<pg, 256, 0, stream>>>(poses, a_in, w_t, params, partials);
  reduce_k<<<rg, 256, 0, stream>>>(partials, red);
  finalize_k<1><<<Bn * On / 256, 256, 0, stream>>>(red, beta_a, beta_u, params, out);
  pass_k<2><<<pg, 256, 0, stream>>>(poses, a_in, w_t, params, partials);
  reduce_k<<<rg, 256, 0, stream>>>(partials, red);
  finalize_k<2><<<Bn * On / 256, 256, 0, stream>>>(red, beta_a, beta_u, params, out);
}